// Round 12
// baseline (48.181 us; speedup 1.0000x reference)
//
#include <hip/hip_runtime.h>
#include <math.h>

#define N_PTS 8192
#define K_CMP 128
#define D_DIM 128

typedef __attribute__((ext_vector_type(8)))  short  short8;    // 8 x bf16
typedef __attribute__((ext_vector_type(8)))  unsigned short ushort8;
typedef __attribute__((ext_vector_type(4)))  unsigned short ushort4v;
typedef __attribute__((ext_vector_type(4)))  float  f32x4;
typedef __attribute__((ext_vector_type(16))) float  f32x16;

static __device__ __forceinline__ unsigned short f2bf(float f) {
    union { float f; unsigned u; } v; v.f = f;
    unsigned r = v.u + 0x7fffu + ((v.u >> 16) & 1u);   // RNE
    return (unsigned short)(r >> 16);
}
static __device__ __forceinline__ float bf2f(unsigned short h) {
    union { unsigned u; float f; } v; v.u = ((unsigned)h) << 16;
    return v.f;
}

// Packed layouts (fragment order -> gmm loads are lane-contiguous 1KB streams):
//   xpack[(rc*8 + es)*64 + lane] (ushort8): X[rc*32 + (lane&31)][es*16 + (lane>>5)*8 ..]
//   Mpack: 24 frags per k, (k*24 + f)*64 + lane:
//     f in 0..19: M'[S*32 + (lane&31)][es*16 + (lane>>5)*8 ..]
//       f -> (S,es): f<2:S=0,b=0; f<6:S=1,b=2; f<12:S=2,b=6; else S=3,b=12; es=f-b
//     f = 20+S: c-column frag: lane lh==0 slot0 = -c[S*32 + (lane&31)], else 0.
//       Used as A in a trailing MFMA with B = bconst (1 in k-slot 0) -> acc += -c.

// ================= prep (coalesced) ==========================================
__global__ void prep_all(const float* __restrict__ x,
                         const float* __restrict__ means,
                         const float* __restrict__ logvar,
                         const float* __restrict__ tri,
                         const float* __restrict__ weigh,
                         unsigned short* __restrict__ Mpack,
                         unsigned short* __restrict__ xpack,
                         float* __restrict__ cvec) {
    const int bid = blockIdx.x;
    const int tid = threadIdx.x;
    const int wave = tid >> 6, lane = tid & 63;
    const int l31 = lane & 31, lh = lane >> 5;

    if (bid >= 256) {
        // ---- X pack: 32 rows, fully coalesced both sides ----
        __shared__ unsigned short Xt[32][136];
        const int b = bid - 256;
        #pragma unroll
        for (int i = 0; i < 4; ++i) {
            const int g  = (i * 256 + tid) * 4;       // elem in 32x128 tile
            const int rl = g >> 7, e = g & 127;
            const float4 v = *(const float4*)&x[(size_t)(b * 32 + rl) * D_DIM + e];
            ushort4v o;
            o.x = f2bf(v.x); o.y = f2bf(v.y); o.z = f2bf(v.z); o.w = f2bf(v.w);
            *(ushort4v*)&Xt[rl][e] = o;
        }
        __syncthreads();
        #pragma unroll
        for (int j = 0; j < 2; ++j) {
            const int es = wave * 2 + j;
            const ushort8 vv = *(const ushort8*)&Xt[l31][es * 16 + lh * 8];
            *(ushort8*)&xpack[((size_t)(b * 8 + es) * 64 + lane) * 8] = vv;
        }
        return;
    }

    // ---- M pack: k = bid>>1, row-half h ----
    __shared__ unsigned short Mt[64][136];
    __shared__ float var_s[D_DIM], mu_s[D_DIM], credu[64];
    const int k = bid >> 1, h = bid & 1;
    const int rbase = h * 64;

    if (tid < D_DIM) {
        var_s[tid] = expf(logvar[k * D_DIM + tid]);
        mu_s[tid]  = means[k * D_DIM + tid];
    }
    if (tid < 64) credu[tid] = 0.f;
    __syncthreads();

    // cvec on h==0, wave 0 (logdet = sum logvar; log_softmax(weigh))
    if (h == 0 && wave == 0) {
        float ld = logvar[k * D_DIM + lane] + logvar[k * D_DIM + lane + 64];
        #pragma unroll
        for (int off = 1; off < 64; off <<= 1) ld += __shfl_xor(ld, off, 64);
        const float w1 = weigh[lane], w2 = weigh[lane + 64];
        float mx = fmaxf(w1, w2);
        #pragma unroll
        for (int off = 1; off < 64; off <<= 1) mx = fmaxf(mx, __shfl_xor(mx, off, 64));
        float se = __expf(w1 - mx) + __expf(w2 - mx);
        #pragma unroll
        for (int off = 1; off < 64; off <<= 1) se += __shfl_xor(se, off, 64);
        if (lane == 0) cvec[k] = ld + (weigh[k] - mx - logf(se));
    }

    // linear coalesced tri reads -> mask/scale -> LDS + c partials (credu = c)
    const size_t kb = (size_t)k * D_DIM * D_DIM;
    #pragma unroll
    for (int i = 0; i < 8; ++i) {
        const int g  = (i * 256 + tid) * 4;           // elem in 64x128 half-tile
        const int rl = g >> 7, e = g & 127;
        const int R  = rbase + rl;
        const float4 v = *(const float4*)&tri[kb + (size_t)R * D_DIM + e];
        const float vals[4] = {v.x, v.y, v.z, v.w};
        ushort4v ob;
        float cacc = 0.f;
        #pragma unroll
        for (int j = 0; j < 4; ++j) {
            const int ee = e + j;
            float val = (ee < R) ? vals[j] * var_s[ee] : (ee == R ? var_s[R] : 0.f);
            const unsigned short bq = f2bf(val);
            ((unsigned short*)&ob)[j] = bq;
            cacc = fmaf(bf2f(bq), mu_s[ee], cacc);
        }
        *(ushort4v*)&Mt[rl][e] = ob;
        atomicAdd(&credu[rl], cacc);
    }
    __syncthreads();

    // packed coalesced writes (M frags of this half)
    const int nf = h ? 14 : 6;
    const int fb = h ? 6 : 0;
    for (int fi = wave; fi < nf; fi += 4) {
        const int f  = fb + fi;
        const int S  = (f < 2) ? 0 : (f < 6) ? 1 : (f < 12) ? 2 : 3;
        const int es = f - ((S == 0) ? 0 : (S == 1) ? 2 : (S == 2) ? 6 : 12);
        const int rl = (S - 2 * h) * 32 + l31;
        const ushort8 vv = *(const ushort8*)&Mt[rl][es * 16 + lh * 8];
        *(ushort8*)&Mpack[((size_t)(k * 24 + f) * 64 + lane) * 8] = vv;
    }

    // c-column frags: this half owns slabs 2h, 2h+1 (waves 0,1)
    if (wave < 2) {
        ushort8 cf = {};
        if (lh == 0) cf[0] = f2bf(-credu[wave * 32 + l31]);
        const int S = 2 * h + wave;
        *(ushort8*)&Mpack[((size_t)(k * 24 + 20 + S) * 64 + lane) * 8] = cf;
    }
}

// ================= main ======================================================
// Block = (one k, n-quarter). 4 waves x 32 n per COMPUTE, 16 COMPUTEs.
// ZERO LDS. M' frags (24, incl. 4 c-column frags) in regs via coalesced asm
// loads; X 2-deep ping-pong (counted vmcnt(8)). Each slab chain ends with
// acc = mfma(c_frag, bconst, acc) -> adds -c[row] (replaces the old LDS-read
// C-operand init: was 16 ds_read_b128/COMPUTE ~= 10 us/CU).
__launch_bounds__(256, 2)
__global__ void gmm_main(const unsigned short* __restrict__ xpack,
                         const unsigned short* __restrict__ Mpack,
                         const float* __restrict__ cvec,
                         float* __restrict__ logits) {
    const int bid = blockIdx.x;
    const int kq  = bid & 7;
    const int ks  = (bid >> 3) & 15;
    const int nq  = bid >> 7;
    const int k   = kq * 16 + ks;
    const int tid = threadIdx.x;
    const int wave = tid >> 6;
    const int lane = tid & 63;
    const int l31  = lane & 31;
    const int lh   = lane >> 5;

    const float cv = cvec[k];

    // ---- M' fragments -> registers (24 coalesced asm loads, pinned) ----
    short8 mf[24];
    {
        const unsigned short* mp = Mpack + ((size_t)k * 24 * 64 + lane) * 8;
        #pragma unroll
        for (int f = 0; f < 24; ++f)
            asm volatile("global_load_dwordx4 %0, %1, off"
                         : "=v"(mf[f]) : "v"(mp + f * 64 * 8) : "memory");
    }

    #define ISSUE_X(Xar, itv) do {                                              \
        const int rc_ = nq * 64 + (itv) * 4 + wave;                             \
        const unsigned short* xp_ = xpack + ((size_t)rc_ * 8 * 64 + lane) * 8;  \
        _Pragma("unroll")                                                       \
        for (int es_ = 0; es_ < 8; ++es_)                                       \
            asm volatile("global_load_dwordx4 %0, %1, off"                      \
                : "=v"(Xar[es_]) : "v"(xp_ + es_ * 64 * 8) : "memory");         \
    } while (0)

    short8 xa[8], xc[8];
    ISSUE_X(xa, 0);
    ISSUE_X(xc, 1);

    // constant B fragment: B[k-slot 0][all cols] = 1.0 (bf16), rest 0
    short8 bconst = {};
    if (lh == 0) bconst[0] = (short)0x3F80;    // bf16 1.0

    // zero C-operand (zeros are trivially rematerializable by RA)
    f32x16 zz;
    #pragma unroll
    for (int r = 0; r < 16; ++r) zz[r] = 0.f;

    asm volatile("s_waitcnt vmcnt(8)" ::: "memory");   // mf + xa landed
    __builtin_amdgcn_sched_barrier(0);

    #define SLAB(S_, B_, NES_, X_) {                                            \
        f32x16 a_ = __builtin_amdgcn_mfma_f32_32x32x16_bf16(mf[B_], X_[0], zz, 0, 0, 0); \
        _Pragma("unroll")                                                       \
        for (int e_ = 1; e_ < NES_; ++e_)                                       \
            a_ = __builtin_amdgcn_mfma_f32_32x32x16_bf16(mf[B_ + e_], X_[e_], a_, 0, 0, 0); \
        a_ = __builtin_amdgcn_mfma_f32_32x32x16_bf16(mf[20 + S_], bconst, a_, 0, 0, 0); \
        _Pragma("unroll")                                                       \
        for (int r_ = 0; r_ < 16; ++r_) {                                       \
            if      ((r_ & 3) == 0) q0 = fmaf(a_[r_], a_[r_], q0);              \
            else if ((r_ & 3) == 1) q1 = fmaf(a_[r_], a_[r_], q1);              \
            else if ((r_ & 3) == 2) q2 = fmaf(a_[r_], a_[r_], q2);              \
            else                    q3 = fmaf(a_[r_], a_[r_], q3); } }

    #define COMPUTE(X_, itv) {                                                  \
        float q0 = 0.f, q1 = 0.f, q2 = 0.f, q3 = 0.f;                           \
        __builtin_amdgcn_s_setprio(1);                                          \
        SLAB(0, 0,  2, X_);                                                     \
        SLAB(1, 2,  4, X_);                                                     \
        SLAB(2, 6,  6, X_);                                                     \
        SLAB(3, 12, 8, X_);                                                     \
        __builtin_amdgcn_s_setprio(0);                                          \
        float q_ = (q0 + q1) + (q2 + q3);                                       \
        q_ += __shfl_xor(q_, 32, 64);                                           \
        qreg[itv] = -0.5f * q_ + cv;                                            \
    }

    float qreg[16];
    #pragma unroll
    for (int it = 0; it < 16; it += 2) {
        COMPUTE(xa, it);                               // consume xa
        if (it + 2 < 16) {
            ISSUE_X(xa, it + 2);                       // refill xa
            asm volatile("s_waitcnt vmcnt(8)" ::: "memory");   // xc ready
        } else {
            asm volatile("s_waitcnt vmcnt(0)" ::: "memory");   // last xc
        }
        __builtin_amdgcn_sched_barrier(0);
        COMPUTE(xc, it + 1);                           // consume xc
        if (it + 3 < 16) {
            ISSUE_X(xc, it + 3);                       // refill xc
            asm volatile("s_waitcnt vmcnt(8)" ::: "memory");   // xa ready
            __builtin_amdgcn_sched_barrier(0);
        }
    }

    // epilogue: one store block (lanes < 32 hold the reduced values)
    if (lane < 32) {
        #pragma unroll
        for (int it = 0; it < 16; ++it)
            logits[(size_t)k * N_PTS + nq * 2048 + it * 128 + wave * 32 + l31] = qreg[it];
    }

    #undef COMPUTE
    #undef SLAB
    #undef ISSUE_X
}

// ================= lse: out[n] = -(logC + logsumexp_k logits[k][n]) ==========
__global__ void lse_kernel(const float* __restrict__ logits, float* __restrict__ out) {
    __shared__ float2 red[8][32];
    const int tid = threadIdx.x;
    const int nl = tid & 31, kc = tid >> 5;
    const int n = blockIdx.x * 32 + nl;
    float m = -INFINITY, s = 0.f;
    #pragma unroll
    for (int j = 0; j < 16; ++j) {
        const float v = logits[(size_t)(kc * 16 + j) * N_PTS + n];
        const float nm = fmaxf(m, v);
        s = s * __expf(m - nm) + __expf(v - nm);
        m = nm;
    }
    red[kc][nl] = make_float2(m, s);
    __syncthreads();
    if (tid < 32) {
        float M = -INFINITY;
        #pragma unroll
        for (int j = 0; j < 8; ++j) M = fmaxf(M, red[j][tid].x);
        float S = 0.f;
        #pragma unroll
        for (int j = 0; j < 8; ++j) S += red[j][tid].y * __expf(red[j][tid].x - M);
        const float logC = -117.62413225f;   // -0.5 * 128 * log(2*pi)
        out[blockIdx.x * 32 + tid] = -(logC + M + logf(S));
    }
}

extern "C" void kernel_launch(void* const* d_in, const int* in_sizes, int n_in,
                              void* d_out, int out_size, void* d_ws, size_t ws_size,
                              hipStream_t stream) {
    const float* x      = (const float*)d_in[0];   // [N, D]
    const float* means  = (const float*)d_in[1];   // [K, D]
    const float* logvar = (const float*)d_in[2];   // [1, K, D]
    const float* tri    = (const float*)d_in[3];   // [1, K, D, D]
    const float* weigh  = (const float*)d_in[4];   // [1, K]
    float* out = (float*)d_out;                    // [N, 1]

    unsigned char* ws = (unsigned char*)d_ws;
    unsigned short* Mpack = (unsigned short*)(ws);                             // 3 MB packed bf16 (24 frags/k)
    unsigned short* xpack = (unsigned short*)(ws + (size_t)4 * 1024 * 1024);   // 2 MB packed bf16
    float*          cvec  = (float*)(ws + (size_t)6 * 1024 * 1024);            // 512 B
    float*          logits = (float*)(ws + (size_t)6 * 1024 * 1024 + 131072);  // 4 MB [K][N]

    hipLaunchKernelGGL(prep_all, dim3(512), dim3(256), 0, stream,
                       x, means, logvar, tri, weigh, Mpack, xpack, cvec);

    hipLaunchKernelGGL(gmm_main, dim3(K_CMP * 4), dim3(256), 0, stream,
                       xpack, Mpack, cvec, logits);

    hipLaunchKernelGGL(lse_kernel, dim3(N_PTS / 32), dim3(256), 0, stream,
                       logits, out);
}

// Round 14
// 44.484 us; speedup vs baseline: 1.0831x; 1.0831x over previous
//
#include <hip/hip_runtime.h>
#include <math.h>

#define N_PTS 8192
#define K_CMP 128
#define D_DIM 128

typedef __attribute__((ext_vector_type(8)))  short  short8;    // 8 x bf16
typedef __attribute__((ext_vector_type(8)))  unsigned short ushort8;
typedef __attribute__((ext_vector_type(4)))  unsigned short ushort4v;
typedef __attribute__((ext_vector_type(4)))  float  f32x4;
typedef __attribute__((ext_vector_type(16))) float  f32x16;

static __device__ __forceinline__ unsigned short f2bf(float f) {
    union { float f; unsigned u; } v; v.f = f;
    unsigned r = v.u + 0x7fffu + ((v.u >> 16) & 1u);   // RNE
    return (unsigned short)(r >> 16);
}
static __device__ __forceinline__ float bf2f(unsigned short h) {
    union { unsigned u; float f; } v; v.u = ((unsigned)h) << 16;
    return v.f;
}

// Packed layouts (fragment order -> gmm loads are lane-contiguous 1KB streams):
//   xpack[(rc*8 + es)*64 + lane] (ushort8): X[rc*32 + (lane&31)][es*16 + (lane>>5)*8 ..]
//   Mpack[(k*20 + f)*64 + lane] (ushort8): M'[S*32 + (lane&31)][es*16 + (lane>>5)*8 ..]
//     f -> (S,es): f<2:S=0,b=0; f<6:S=1,b=2; f<12:S=2,b=6; else S=3,b=12; es=f-b

// ================= prep (coalesced) ==========================================
__global__ void prep_all(const float* __restrict__ x,
                         const float* __restrict__ means,
                         const float* __restrict__ logvar,
                         const float* __restrict__ tri,
                         const float* __restrict__ weigh,
                         unsigned short* __restrict__ Mpack,
                         unsigned short* __restrict__ xpack,
                         float* __restrict__ cneg,
                         float* __restrict__ cvec) {
    const int bid = blockIdx.x;
    const int tid = threadIdx.x;
    const int wave = tid >> 6, lane = tid & 63;
    const int l31 = lane & 31, lh = lane >> 5;

    if (bid >= 256) {
        // ---- X pack: 32 rows, fully coalesced both sides ----
        __shared__ unsigned short Xt[32][136];
        const int b = bid - 256;
        #pragma unroll
        for (int i = 0; i < 4; ++i) {
            const int g  = (i * 256 + tid) * 4;       // elem in 32x128 tile
            const int rl = g >> 7, e = g & 127;
            const float4 v = *(const float4*)&x[(size_t)(b * 32 + rl) * D_DIM + e];
            ushort4v o;
            o.x = f2bf(v.x); o.y = f2bf(v.y); o.z = f2bf(v.z); o.w = f2bf(v.w);
            *(ushort4v*)&Xt[rl][e] = o;
        }
        __syncthreads();
        #pragma unroll
        for (int j = 0; j < 2; ++j) {
            const int es = wave * 2 + j;
            const ushort8 vv = *(const ushort8*)&Xt[l31][es * 16 + lh * 8];
            *(ushort8*)&xpack[((size_t)(b * 8 + es) * 64 + lane) * 8] = vv;
        }
        return;
    }

    // ---- M pack: k = bid>>1, row-half h ----
    __shared__ unsigned short Mt[64][136];
    __shared__ float var_s[D_DIM], mu_s[D_DIM], credu[64];
    const int k = bid >> 1, h = bid & 1;
    const int rbase = h * 64;

    if (tid < D_DIM) {
        var_s[tid] = expf(logvar[k * D_DIM + tid]);
        mu_s[tid]  = means[k * D_DIM + tid];
    }
    if (tid < 64) credu[tid] = 0.f;
    __syncthreads();

    // cvec on h==0, wave 0 (logdet = sum logvar; log_softmax(weigh))
    if (h == 0 && wave == 0) {
        float ld = logvar[k * D_DIM + lane] + logvar[k * D_DIM + lane + 64];
        #pragma unroll
        for (int off = 1; off < 64; off <<= 1) ld += __shfl_xor(ld, off, 64);
        const float w1 = weigh[lane], w2 = weigh[lane + 64];
        float mx = fmaxf(w1, w2);
        #pragma unroll
        for (int off = 1; off < 64; off <<= 1) mx = fmaxf(mx, __shfl_xor(mx, off, 64));
        float se = __expf(w1 - mx) + __expf(w2 - mx);
        #pragma unroll
        for (int off = 1; off < 64; off <<= 1) se += __shfl_xor(se, off, 64);
        if (lane == 0) cvec[k] = ld + (weigh[k] - mx - logf(se));
    }

    // linear coalesced tri reads -> mask/scale -> LDS + cneg partials
    const size_t kb = (size_t)k * D_DIM * D_DIM;
    #pragma unroll
    for (int i = 0; i < 8; ++i) {
        const int g  = (i * 256 + tid) * 4;           // elem in 64x128 half-tile
        const int rl = g >> 7, e = g & 127;
        const int R  = rbase + rl;
        const float4 v = *(const float4*)&tri[kb + (size_t)R * D_DIM + e];
        const float vals[4] = {v.x, v.y, v.z, v.w};
        ushort4v ob;
        float cacc = 0.f;
        #pragma unroll
        for (int j = 0; j < 4; ++j) {
            const int ee = e + j;
            float val = (ee < R) ? vals[j] * var_s[ee] : (ee == R ? var_s[R] : 0.f);
            const unsigned short bq = f2bf(val);
            ((unsigned short*)&ob)[j] = bq;
            cacc = fmaf(bf2f(bq), mu_s[ee], cacc);
        }
        *(ushort4v*)&Mt[rl][e] = ob;
        atomicAdd(&credu[rl], cacc);
    }
    __syncthreads();

    // packed coalesced writes (frags of this half)
    const int nf = h ? 14 : 6;
    const int fb = h ? 6 : 0;
    for (int fi = wave; fi < nf; fi += 4) {
        const int f  = fb + fi;
        const int S  = (f < 2) ? 0 : (f < 6) ? 1 : (f < 12) ? 2 : 3;
        const int es = f - ((S == 0) ? 0 : (S == 1) ? 2 : (S == 2) ? 6 : 12);
        const int rl = (S - 2 * h) * 32 + l31;
        const ushort8 vv = *(const ushort8*)&Mt[rl][es * 16 + lh * 8];
        *(ushort8*)&Mpack[((size_t)(k * 20 + f) * 64 + lane) * 8] = vv;
    }
    if (tid < 64) cneg[k * D_DIM + rbase + tid] = -credu[tid];
}

// ================= main ======================================================
// Block = (one k, n-EIGHTH = 1024 rows). 4 waves x 32 n per COMPUTE, 8
// COMPUTEs. Grid 1024 blocks -> 4 blocks/CU = 16 waves/CU (was 8): the
// vmcnt stall of one wave is covered by 3 others per SIMD (TLP, not ILP --
// deeper register rings crash the toolchain). Structure otherwise = r9.
__launch_bounds__(256, 2)
__global__ void gmm_main(const unsigned short* __restrict__ xpack,
                         const unsigned short* __restrict__ Mpack,
                         const float* __restrict__ cneg,
                         const float* __restrict__ cvec,
                         float* __restrict__ logits) {
    __shared__ __align__(16) float cs[D_DIM];    // -c row, broadcast-read

    const int bid = blockIdx.x;
    const int kq  = bid & 7;          // XCD-pinned k-chunks
    const int ks  = (bid >> 3) & 15;
    const int n8  = bid >> 7;         // n-eighth 0..7
    const int k   = kq * 16 + ks;
    const int it0 = n8 * 8;           // global 128-row chunk base
    const int tid = threadIdx.x;
    const int wave = tid >> 6;
    const int lane = tid & 63;
    const int l31  = lane & 31;
    const int lh   = lane >> 5;

    const float cv = cvec[k];

    // cs staged first (its compiler-emitted waitcnt lands before asm loads);
    // each wave writes the full copy -> wave-local dependency only.
    if (lane < 32) ((float4*)cs)[lane] = ((const float4*)(cneg + (size_t)k * D_DIM))[lane];

    // ---- M' fragments -> registers (20 coalesced asm loads, pinned) ----
    short8 mf[20];
    {
        const unsigned short* mp = Mpack + ((size_t)k * 20 * 64 + lane) * 8;
        #pragma unroll
        for (int f = 0; f < 20; ++f)
            asm volatile("global_load_dwordx4 %0, %1, off"
                         : "=v"(mf[f]) : "v"(mp + f * 64 * 8) : "memory");
    }

    #define ISSUE_X(Xar, itv) do {                                              \
        const int rc_ = (it0 + (itv)) * 4 + wave;                               \
        const unsigned short* xp_ = xpack + ((size_t)rc_ * 8 * 64 + lane) * 8;  \
        _Pragma("unroll")                                                       \
        for (int es_ = 0; es_ < 8; ++es_)                                       \
            asm volatile("global_load_dwordx4 %0, %1, off"                      \
                : "=v"(Xar[es_]) : "v"(xp_ + es_ * 64 * 8) : "memory");         \
    } while (0)

    short8 xa[8], xc[8];
    ISSUE_X(xa, 0);
    ISSUE_X(xc, 1);
    asm volatile("s_waitcnt vmcnt(8)" ::: "memory");   // mf + cs + xa landed
    __builtin_amdgcn_sched_barrier(0);

    #define SLAB(S_, B_, NES_, X_) {                                            \
        f32x16 ci_;                                                             \
        _Pragma("unroll")                                                       \
        for (int j_ = 0; j_ < 4; ++j_) {                                        \
            const f32x4 c_ = *(const f32x4*)&cs[(S_) * 32 + 8 * j_ + 4 * lh];   \
            ci_[4*j_+0] = c_.x; ci_[4*j_+1] = c_.y;                             \
            ci_[4*j_+2] = c_.z; ci_[4*j_+3] = c_.w; }                           \
        f32x16 a_ = __builtin_amdgcn_mfma_f32_32x32x16_bf16(mf[B_], X_[0], ci_, 0, 0, 0); \
        _Pragma("unroll")                                                       \
        for (int e_ = 1; e_ < NES_; ++e_)                                       \
            a_ = __builtin_amdgcn_mfma_f32_32x32x16_bf16(mf[B_ + e_], X_[e_], a_, 0, 0, 0); \
        _Pragma("unroll")                                                       \
        for (int r_ = 0; r_ < 16; ++r_) {                                       \
            if      ((r_ & 3) == 0) q0 = fmaf(a_[r_], a_[r_], q0);              \
            else if ((r_ & 3) == 1) q1 = fmaf(a_[r_], a_[r_], q1);              \
            else if ((r_ & 3) == 2) q2 = fmaf(a_[r_], a_[r_], q2);              \
            else                    q3 = fmaf(a_[r_], a_[r_], q3); } }

    #define COMPUTE(X_, itv) {                                                  \
        float q0 = 0.f, q1 = 0.f, q2 = 0.f, q3 = 0.f;                           \
        __builtin_amdgcn_s_setprio(1);                                          \
        SLAB(0, 0,  2, X_);                                                     \
        SLAB(1, 2,  4, X_);                                                     \
        SLAB(2, 6,  6, X_);                                                     \
        SLAB(3, 12, 8, X_);                                                     \
        __builtin_amdgcn_s_setprio(0);                                          \
        float q_ = (q0 + q1) + (q2 + q3);                                       \
        q_ += __shfl_xor(q_, 32, 64);                                           \
        qreg[itv] = -0.5f * q_ + cv;                                            \
    }

    float qreg[8];
    #pragma unroll
    for (int it = 0; it < 8; it += 2) {
        COMPUTE(xa, it);                               // consume xa
        if (it + 2 < 8) {
            ISSUE_X(xa, it + 2);                       // refill xa
            asm volatile("s_waitcnt vmcnt(8)" ::: "memory");   // xc ready
        } else {
            asm volatile("s_waitcnt vmcnt(0)" ::: "memory");   // last xc
        }
        __builtin_amdgcn_sched_barrier(0);
        COMPUTE(xc, it + 1);                           // consume xc
        if (it + 3 < 8) {
            ISSUE_X(xc, it + 3);                       // refill xc
            asm volatile("s_waitcnt vmcnt(8)" ::: "memory");   // xa ready
            __builtin_amdgcn_sched_barrier(0);
        }
    }

    // epilogue: one store block (lanes < 32 hold the reduced values)
    if (lane < 32) {
        #pragma unroll
        for (int it = 0; it < 8; ++it)
            logits[(size_t)k * N_PTS + (it0 + it) * 128 + wave * 32 + l31] = qreg[it];
    }

    #undef COMPUTE
    #undef SLAB
    #undef ISSUE_X
}

// ================= lse: out[n] = -(logC + logsumexp_k logits[k][n]) ==========
__global__ void lse_kernel(const float* __restrict__ logits, float* __restrict__ out) {
    __shared__ float2 red[8][32];
    const int tid = threadIdx.x;
    const int nl = tid & 31, kc = tid >> 5;
    const int n = blockIdx.x * 32 + nl;
    float m = -INFINITY, s = 0.f;
    #pragma unroll
    for (int j = 0; j < 16; ++j) {
        const float v = logits[(size_t)(kc * 16 + j) * N_PTS + n];
        const float nm = fmaxf(m, v);
        s = s * __expf(m - nm) + __expf(v - nm);
        m = nm;
    }
    red[kc][nl] = make_float2(m, s);
    __syncthreads();
    if (tid < 32) {
        float M = -INFINITY;
        #pragma unroll
        for (int j = 0; j < 8; ++j) M = fmaxf(M, red[j][tid].x);
        float S = 0.f;
        #pragma unroll
        for (int j = 0; j < 8; ++j) S += red[j][tid].y * __expf(red[j][tid].x - M);
        const float logC = -117.62413225f;   // -0.5 * 128 * log(2*pi)
        out[blockIdx.x * 32 + tid] = -(logC + M + logf(S));
    }
}

extern "C" void kernel_launch(void* const* d_in, const int* in_sizes, int n_in,
                              void* d_out, int out_size, void* d_ws, size_t ws_size,
                              hipStream_t stream) {
    const float* x      = (const float*)d_in[0];   // [N, D]
    const float* means  = (const float*)d_in[1];   // [K, D]
    const float* logvar = (const float*)d_in[2];   // [1, K, D]
    const float* tri    = (const float*)d_in[3];   // [1, K, D, D]
    const float* weigh  = (const float*)d_in[4];   // [1, K]
    float* out = (float*)d_out;                    // [N, 1]

    unsigned char* ws = (unsigned char*)d_ws;
    unsigned short* Mpack = (unsigned short*)(ws);                             // 2.56 MB packed bf16
    unsigned short* xpack = (unsigned short*)(ws + (size_t)4 * 1024 * 1024);   // 2 MB packed bf16
    float*          cneg  = (float*)(ws + (size_t)6 * 1024 * 1024);            // 64 KB
    float*          cvec  = (float*)(ws + (size_t)6 * 1024 * 1024 + 65536);    // 512 B
    float*          logits = (float*)(ws + (size_t)6 * 1024 * 1024 + 131072);  // 4 MB [K][N]

    hipLaunchKernelGGL(prep_all, dim3(512), dim3(256), 0, stream,
                       x, means, logvar, tri, weigh, Mpack, xpack, cneg, cvec);

    hipLaunchKernelGGL(gmm_main, dim3(K_CMP * 8), dim3(256), 0, stream,
                       xpack, Mpack, cneg, cvec, logits);

    hipLaunchKernelGGL(lse_kernel, dim3(N_PTS / 32), dim3(256), 0, stream,
                       logits, out);
}

// Round 15
// 41.968 us; speedup vs baseline: 1.1481x; 1.0600x over previous
//
#include <hip/hip_runtime.h>
#include <math.h>

#define N_PTS 8192
#define K_CMP 128
#define D_DIM 128

typedef __attribute__((ext_vector_type(8)))  short  short8;    // 8 x bf16
typedef __attribute__((ext_vector_type(8)))  unsigned short ushort8;
typedef __attribute__((ext_vector_type(4)))  unsigned short ushort4v;
typedef __attribute__((ext_vector_type(4)))  float  f32x4;
typedef __attribute__((ext_vector_type(16))) float  f32x16;

static __device__ __forceinline__ unsigned short f2bf(float f) {
    union { float f; unsigned u; } v; v.f = f;
    unsigned r = v.u + 0x7fffu + ((v.u >> 16) & 1u);   // RNE
    return (unsigned short)(r >> 16);
}
static __device__ __forceinline__ float bf2f(unsigned short h) {
    union { unsigned u; float f; } v; v.u = ((unsigned)h) << 16;
    return v.f;
}

// Packed layouts (fragment order so gmm loads are lane-contiguous 1KB streams):
//   xpack[(rc*8 + es)*64 + lane] (ushort8): X[rc*32 + (lane&31)][es*16 + (lane>>5)*8 .. +7]
//   Mpack[(k*20 + f)*64 + lane] (ushort8): M'[S*32 + (lane&31)][es*16 + (lane>>5)*8 .. +7]
//     f -> (S, es): f<2:S=0,b=0; f<6:S=1,b=2; f<12:S=2,b=6; else S=3,b=12; es=f-b

// ================= prep (fused): blocks 0..127 -> M'/cneg/cvec for k=bid;
//                  blocks 128..255 -> x fp32 -> packed bf16 ==================
__global__ void prep_all(const float* __restrict__ x,
                         const float* __restrict__ means,
                         const float* __restrict__ logvar,
                         const float* __restrict__ tri,
                         const float* __restrict__ weigh,
                         unsigned short* __restrict__ Mpack,
                         unsigned short* __restrict__ xpack,
                         float* __restrict__ cneg,
                         float* __restrict__ cvec) {
    const int bid = blockIdx.x;
    const int tid = threadIdx.x;
    const int wave = tid >> 6, lane = tid & 63;
    const int l31 = lane & 31, lh = lane >> 5;

    if (bid >= K_CMP) {
        // X pack: block handles rowchunks rc0, rc0+1 (2 x 32 rows)
        const int rc0 = (bid - K_CMP) * 2;
        #pragma unroll
        for (int j = 0; j < 4; ++j) {
            const int t  = wave * 4 + j;          // 0..15
            const int rc = rc0 + (t >> 3);
            const int es = t & 7;
            const int n  = rc * 32 + l31;
            const int e0 = es * 16 + lh * 8;
            const float4 v0 = *(const float4*)&x[(size_t)n * D_DIM + e0];
            const float4 v1 = *(const float4*)&x[(size_t)n * D_DIM + e0 + 4];
            ushort8 o;
            o[0] = f2bf(v0.x); o[1] = f2bf(v0.y); o[2] = f2bf(v0.z); o[3] = f2bf(v0.w);
            o[4] = f2bf(v1.x); o[5] = f2bf(v1.y); o[6] = f2bf(v1.z); o[7] = f2bf(v1.w);
            *(ushort8*)&xpack[((size_t)(rc * 8 + es) * 64 + lane) * 8] = o;
        }
        return;
    }

    const int k = bid;
    __shared__ float var_s[D_DIM], mu_s[D_DIM], credu[D_DIM];
    if (tid < D_DIM) {
        var_s[tid] = expf(logvar[k * D_DIM + tid]);
        mu_s[tid]  = means[k * D_DIM + tid];
        credu[tid] = 0.f;
    }
    __syncthreads();

    // wave 0: cvec[k] = logdet + log_softmax(weigh)[k]
    if (wave == 0) {
        float ld = logf(fabsf(var_s[lane]) + 1e-8f) +
                   logf(fabsf(var_s[lane + 64]) + 1e-8f);
        #pragma unroll
        for (int off = 1; off < 64; off <<= 1) ld += __shfl_xor(ld, off, 64);
        const float w1 = weigh[lane], w2 = weigh[lane + 64];
        float mx = fmaxf(w1, w2);
        #pragma unroll
        for (int off = 1; off < 64; off <<= 1) mx = fmaxf(mx, __shfl_xor(mx, off, 64));
        float se = __expf(w1 - mx) + __expf(w2 - mx);
        #pragma unroll
        for (int off = 1; off < 64; off <<= 1) se += __shfl_xor(se, off, 64);
        if (lane == 0) cvec[k] = ld + (weigh[k] - mx - logf(se));
    }

    // all waves: 5 frags each of M' (packed), + cneg row-partials via LDS atomics
    const size_t kb = (size_t)k * D_DIM * D_DIM;
    #pragma unroll
    for (int j = 0; j < 5; ++j) {
        const int f = wave * 5 + j;               // 0..19
        const int S = (f < 2) ? 0 : (f < 6) ? 1 : (f < 12) ? 2 : 3;
        const int b = (S == 0) ? 0 : (S == 1) ? 2 : (S == 2) ? 6 : 12;
        const int es = f - b;
        const int r  = S * 32 + l31;
        const int e0 = es * 16 + lh * 8;
        const float4 v0 = *(const float4*)&tri[kb + (size_t)r * D_DIM + e0];
        const float4 v1 = *(const float4*)&tri[kb + (size_t)r * D_DIM + e0 + 4];
        const float vals[8] = {v0.x, v0.y, v0.z, v0.w, v1.x, v1.y, v1.z, v1.w};
        ushort8 ob;
        float cacc = 0.f;
        #pragma unroll
        for (int jj = 0; jj < 8; ++jj) {
            const int ee = e0 + jj;
            float val = (ee < r) ? vals[jj] * var_s[ee] : (ee == r ? var_s[r] : 0.f);
            unsigned short bq = f2bf(val);
            ob[jj] = bq;
            cacc = fmaf(bf2f(bq), mu_s[ee], cacc);
        }
        *(ushort8*)&Mpack[((size_t)(k * 20 + f) * 64 + lane) * 8] = ob;
        atomicAdd(&credu[r], cacc);
    }
    __syncthreads();
    if (tid < D_DIM) cneg[k * D_DIM + tid] = -credu[tid];
}

// ================= main ======================================================
// Block = (one k, n-quarter of 2048). 4 waves x 32 n per iter, 16 iters.
// M' fragments in registers (20 short8, coalesced packed loads); X streamed
// from L2 as contiguous 1KB-per-instruction packed loads, vmcnt(8) ping-pong.
// No barriers anywhere; cs (ci source) is per-wave-redundant LDS.
__launch_bounds__(256, 2)
__global__ void gmm_main(const unsigned short* __restrict__ xpack,
                         const unsigned short* __restrict__ Mpack,
                         const float* __restrict__ cneg,
                         const float* __restrict__ cvec,
                         float* __restrict__ logits) {
    __shared__ __align__(16) float cs[D_DIM];    // -c row, broadcast-read

    const int bid = blockIdx.x;
    const int k   = bid >> 2;
    const int nq  = bid & 3;
    const int tid = threadIdx.x;
    const int wave = tid >> 6;
    const int lane = tid & 63;
    const int l31  = lane & 31;
    const int lh   = lane >> 5;

    const float cv = cvec[k];

    // cs staged FIRST (compiler's own vmcnt wait lands before any asm loads);
    // every wave writes the full copy -> no cross-wave dep, no barrier needed.
    if (lane < 32) ((float4*)cs)[lane] = ((const float4*)(cneg + (size_t)k * D_DIM))[lane];

    // ---- M' fragments -> registers (20 coalesced asm loads, pinned) ----
    short8 mf[20];
    {
        const unsigned short* mp = Mpack + ((size_t)k * 20 * 64 + lane) * 8;
        #pragma unroll
        for (int f = 0; f < 20; ++f)
            asm volatile("global_load_dwordx4 %0, %1, off"
                         : "=v"(mf[f]) : "v"(mp + f * 64 * 8) : "memory");
    }

    #define ISSUE_X(Xar, itv) do {                                              \
        const int rc_ = nq * 64 + ((itv) & 15) * 4 + wave;                      \
        const unsigned short* xp_ = xpack + ((size_t)rc_ * 8 * 64 + lane) * 8;  \
        _Pragma("unroll")                                                       \
        for (int es_ = 0; es_ < 8; ++es_)                                       \
            asm volatile("global_load_dwordx4 %0, %1, off"                      \
                : "=v"(Xar[es_]) : "v"(xp_ + es_ * 64 * 8) : "memory");         \
    } while (0)

    short8 xa[8], xc[8];
    ISSUE_X(xa, 0);
    ISSUE_X(xc, 1);
    asm volatile("s_waitcnt vmcnt(8)" ::: "memory");   // mf + xa landed
    __builtin_amdgcn_sched_barrier(0);

    // ---- per-slab MFMA + q accumulation ----
    #define SLAB(S_, B_, NES_, X_) {                                            \
        f32x16 ci_;                                                             \
        _Pragma("unroll")                                                       \
        for (int j_ = 0; j_ < 4; ++j_) {                                        \
            const f32x4 c_ = *(const f32x4*)&cs[S_ * 32 + 8 * j_ + 4 * lh];     \
            ci_[4*j_+0] = c_.x; ci_[4*j_+1] = c_.y;                             \
            ci_[4*j_+2] = c_.z; ci_[4*j_+3] = c_.w; }                           \
        f32x16 a_ = __builtin_amdgcn_mfma_f32_32x32x16_bf16(mf[B_], X_[0], ci_, 0, 0, 0); \
        _Pragma("unroll")                                                       \
        for (int e_ = 1; e_ < NES_; ++e_)                                       \
            a_ = __builtin_amdgcn_mfma_f32_32x32x16_bf16(mf[B_ + e_], X_[e_], a_, 0, 0, 0); \
        _Pragma("unroll")                                                       \
        for (int r_ = 0; r_ < 16; ++r_) {                                       \
            if      ((r_ & 3) == 0) q0 = fmaf(a_[r_], a_[r_], q0);              \
            else if ((r_ & 3) == 1) q1 = fmaf(a_[r_], a_[r_], q1);              \
            else if ((r_ & 3) == 2) q2 = fmaf(a_[r_], a_[r_], q2);              \
            else                    q3 = fmaf(a_[r_], a_[r_], q3); } }

    #define COMPUTE(X_, itv) {                                                  \
        float q0 = 0.f, q1 = 0.f, q2 = 0.f, q3 = 0.f;                           \
        __builtin_amdgcn_s_setprio(1);                                          \
        SLAB(0, 0,  2, X_);                                                     \
        SLAB(1, 2,  4, X_);                                                     \
        SLAB(2, 6,  6, X_);                                                     \
        SLAB(3, 12, 8, X_);                                                     \
        __builtin_amdgcn_s_setprio(0);                                          \
        float q_ = (q0 + q1) + (q2 + q3);                                       \
        q_ += __shfl_xor(q_, 32, 64);                                           \
        const int n_ = nq * 2048 + (itv) * 128 + wave * 32 + l31;               \
        if (lane < 32) logits[(size_t)k * N_PTS + n_] = -0.5f * q_ + cv;        \
    }

    #pragma unroll 1
    for (int it = 0; it < 16; it += 2) {
        COMPUTE(xa, it);                 // consume xa (store: +1 vm)
        ISSUE_X(xa, it + 2);             // refill xa
        asm volatile("s_waitcnt vmcnt(8)" ::: "memory");   // xc ready
        __builtin_amdgcn_sched_barrier(0);
        COMPUTE(xc, it + 1);
        ISSUE_X(xc, it + 3);
        asm volatile("s_waitcnt vmcnt(8)" ::: "memory");   // xa ready
        __builtin_amdgcn_sched_barrier(0);
    }
    asm volatile("s_waitcnt vmcnt(0)" ::: "memory");       // drain tail dummies

    #undef COMPUTE
    #undef SLAB
    #undef ISSUE_X
}

// ================= lse: out[n] = -(logC + logsumexp_k logits[k][n]) ==========
__global__ void lse_kernel(const float* __restrict__ logits, float* __restrict__ out) {
    __shared__ float2 red[8][32];
    const int tid = threadIdx.x;
    const int nl = tid & 31, kc = tid >> 5;
    const int n = blockIdx.x * 32 + nl;
    float m = -INFINITY, s = 0.f;
    #pragma unroll
    for (int j = 0; j < 16; ++j) {
        const float v = logits[(size_t)(kc * 16 + j) * N_PTS + n];
        const float nm = fmaxf(m, v);
        s = s * __expf(m - nm) + __expf(v - nm);
        m = nm;
    }
    red[kc][nl] = make_float2(m, s);
    __syncthreads();
    if (tid < 32) {
        float M = -INFINITY;
        #pragma unroll
        for (int j = 0; j < 8; ++j) M = fmaxf(M, red[j][tid].x);
        float S = 0.f;
        #pragma unroll
        for (int j = 0; j < 8; ++j) S += red[j][tid].y * __expf(red[j][tid].x - M);
        const float logC = -117.62413225f;   // -0.5 * 128 * log(2*pi)
        out[blockIdx.x * 32 + tid] = -(logC + M + logf(S));
    }
}

extern "C" void kernel_launch(void* const* d_in, const int* in_sizes, int n_in,
                              void* d_out, int out_size, void* d_ws, size_t ws_size,
                              hipStream_t stream) {
    const float* x      = (const float*)d_in[0];   // [N, D]
    const float* means  = (const float*)d_in[1];   // [K, D]
    const float* logvar = (const float*)d_in[2];   // [1, K, D]
    const float* tri    = (const float*)d_in[3];   // [1, K, D, D]
    const float* weigh  = (const float*)d_in[4];   // [1, K]
    float* out = (float*)d_out;                    // [N, 1]

    unsigned char* ws = (unsigned char*)d_ws;
    unsigned short* Mpack = (unsigned short*)(ws);                             // 2.56 MB packed bf16
    unsigned short* xpack = (unsigned short*)(ws + (size_t)4 * 1024 * 1024);   // 2 MB packed bf16
    float*          cneg  = (float*)(ws + (size_t)6 * 1024 * 1024);            // 64 KB
    float*          cvec  = (float*)(ws + (size_t)6 * 1024 * 1024 + 65536);    // 512 B
    float*          logits = (float*)(ws + (size_t)6 * 1024 * 1024 + 131072);  // 4 MB [K][N]

    hipLaunchKernelGGL(prep_all, dim3(256), dim3(256), 0, stream,
                       x, means, logvar, tri, weigh, Mpack, xpack, cneg, cvec);

    hipLaunchKernelGGL(gmm_main, dim3(K_CMP * 4), dim3(256), 0, stream,
                       xpack, Mpack, cneg, cvec, logits);

    hipLaunchKernelGGL(lse_kernel, dim3(N_PTS / 32), dim3(256), 0, stream,
                       logits, out);
}